// Round 9
// baseline (1944.213 us; speedup 1.0000x reference)
//
#include <hip/hip_runtime.h>

#define N_NODES 100000
#define N_EDGES 1600000
#define N_GRAPHS 256
#define NODE_F 92
#define EDGE_F 41
#define HID 64
#define NCHUNK 98  // ceil(100000/1024)

typedef float f2 __attribute__((ext_vector_type(2)));
typedef float f4 __attribute__((ext_vector_type(4)));

// ---------------------------------------------------------------------------
// K1: h = relu(x @ emb_W + emb_b); one wave/node, lane = channel.
// Node index forced to SGPR -> x row reads become s_load (rows 368B, 16B-aligned).
// ---------------------------------------------------------------------------
__global__ __launch_bounds__(256) void k_embed(const float* __restrict__ x,
                                               const float* __restrict__ W,
                                               const float* __restrict__ b,
                                               float* __restrict__ h) {
    __shared__ float sT[23 * 256];  // transposed: one ds_read_b128 per 4 k's
    for (int i = threadIdx.x; i < 23 * 256; i += 256) {
        const int kq = i >> 8, rem = i & 255, ln = rem >> 2, kk = rem & 3;
        sT[i] = W[(4 * kq + kk) * HID + ln];
    }
    __syncthreads();
    const int lane = threadIdx.x & 63;
    const int nW   = gridDim.x * 4;
    const float bias = b[lane];
    for (int n0 = blockIdx.x * 4 + (threadIdx.x >> 6); n0 < N_NODES; n0 += nW) {
        const int n = __builtin_amdgcn_readfirstlane(n0);
        const float* xr = x + (size_t)n * NODE_F;
        float acc = bias;
#pragma unroll
        for (int k0 = 0; k0 < NODE_F; k0 += 4) {
            const f4 xv = *(const f4*)&xr[k0];
            const f4 wv = *(const f4*)&sT[(k0 >> 2) * 256 + 4 * lane];
            acc = fmaf(xv.x, wv.x, acc);
            acc = fmaf(xv.y, wv.y, acc);
            acc = fmaf(xv.z, wv.z, acc);
            acc = fmaf(xv.w, wv.w, acc);
        }
        h[(size_t)n * HID + lane] = fmaxf(acc, 0.f);
    }
}

// ---------------------------------------------------------------------------
// CSR build: counting sort of edges by dst.
// ---------------------------------------------------------------------------
__global__ __launch_bounds__(256) void k_hist(const int* __restrict__ ei,
                                              int* __restrict__ cnt) {
    for (int i = blockIdx.x * 256 + threadIdx.x; i < N_EDGES; i += gridDim.x * 256)
        atomicAdd(&cnt[ei[N_EDGES + i]], 1);
}

__global__ __launch_bounds__(256) void k_scan1(const int* __restrict__ cnt,
                                               int* __restrict__ csum) {
    __shared__ int red[256];
    const int b = blockIdx.x, t = threadIdx.x;
    int s = 0;
    for (int i = t; i < 1024; i += 256) {
        const int g = b * 1024 + i;
        s += (g < N_NODES) ? cnt[g] : 0;
    }
    red[t] = s;
    __syncthreads();
    for (int off = 128; off > 0; off >>= 1) {
        if (t < off) red[t] += red[t + off];
        __syncthreads();
    }
    if (t == 0) csum[b] = red[0];
}

__global__ __launch_bounds__(128) void k_scan2(const int* __restrict__ csum,
                                               int* __restrict__ cbase) {
    __shared__ int sh[128];
    const int t = threadIdx.x;
    const int v0 = (t < NCHUNK) ? csum[t] : 0;
    sh[t] = v0;
    __syncthreads();
    for (int off = 1; off < 128; off <<= 1) {
        const int v = (t >= off) ? sh[t - off] : 0;
        __syncthreads();
        sh[t] += v;
        __syncthreads();
    }
    if (t < NCHUNK) cbase[t] = sh[t] - v0;  // exclusive
}

__global__ __launch_bounds__(256) void k_scan3(const int* __restrict__ cnt,
                                               const int* __restrict__ cbase,
                                               int* __restrict__ offs,
                                               int* __restrict__ woffs) {
    __shared__ int sh[256];
    const int b = blockIdx.x, t = threadIdx.x;
    const int g0 = b * 1024 + t * 4;
    int v[4], s = 0;
#pragma unroll
    for (int k = 0; k < 4; ++k) {
        const int g = g0 + k;
        v[k] = (g < N_NODES) ? cnt[g] : 0;
        s += v[k];
    }
    sh[t] = s;
    __syncthreads();
    for (int off = 1; off < 256; off <<= 1) {
        const int x = (t >= off) ? sh[t - off] : 0;
        __syncthreads();
        sh[t] += x;
        __syncthreads();
    }
    int base = cbase[b] + sh[t] - s;
#pragma unroll
    for (int k = 0; k < 4; ++k) {
        const int g = g0 + k;
        if (g < N_NODES) { offs[g] = base; woffs[g] = base; }
        base += v[k];
    }
    if (b == 0 && t == 0) offs[N_NODES] = N_EDGES;
}

__global__ __launch_bounds__(256) void k_scatter(const int* __restrict__ ei,
                                                 int* __restrict__ woffs,
                                                 int2* __restrict__ csr) {
    for (int i = blockIdx.x * 256 + threadIdx.x; i < N_EDGES; i += gridDim.x * 256) {
        const int src = ei[i];
        const int dst = ei[N_EDGES + i];
        const int pos = atomicAdd(&woffs[dst], 1);
        csr[pos] = make_int2(src, i);
    }
}

// ---------------------------------------------------------------------------
// K2 (per layer): node precompute.  For node n, channel c (=lane):
//   D[n][2c+0] = h[n].Wf[0:64,c]     D[n][2c+1] = h[n].Ws[0:64,c]
//   S[n][2c+0] = h[n].Wf[64:128,c]   S[n][2c+1] = h[n].Ws[64:128,c]
// LDS row k, lane c: {Wf[k][c],Ws[k][c],Wf[64+k][c],Ws[64+k][c]} -> ds_read_b128.
// RELU_IN=1: relu applied on the fly, rows rewritten in place (wave owns row).
// ---------------------------------------------------------------------------
template <int RELU_IN>
__global__ __launch_bounds__(256) void k_node_pre(const float* hin,
                                                  float* hout,
                                                  const float* __restrict__ Wf,
                                                  const float* __restrict__ Ws,
                                                  float* __restrict__ D,
                                                  float* __restrict__ S) {
    __shared__ float sW[64 * 256];  // 64 KB
    for (int i = threadIdx.x; i < 64 * 256; i += 256) {
        const int k = i >> 8, j = i & 255, c = j >> 2, r = j & 3;
        float v;
        if (r == 0)      v = Wf[k * HID + c];
        else if (r == 1) v = Ws[k * HID + c];
        else if (r == 2) v = Wf[(64 + k) * HID + c];
        else             v = Ws[(64 + k) * HID + c];
        sW[i] = v;
    }
    __syncthreads();
    const int lane = threadIdx.x & 63;
    const int wave = blockIdx.x * 4 + (threadIdx.x >> 6);
    const int nW   = gridDim.x * 4;
    for (int base0 = wave * 8; base0 < N_NODES; base0 += nW * 8) {  // 100000%8==0
        const int base = __builtin_amdgcn_readfirstlane(base0);
        float aD0[8] = {}, aD1[8] = {}, aS0[8] = {}, aS1[8] = {};
        for (int k0 = 0; k0 < HID; k0 += 4) {
            f4 wv[4];
#pragma unroll
            for (int kk = 0; kk < 4; ++kk)
                wv[kk] = *(const f4*)&sW[(k0 + kk) * 256 + 4 * lane];
#pragma unroll
            for (int m = 0; m < 8; ++m) {
                f4 hv = *(const f4*)&hin[(size_t)(base + m) * HID + k0];
                if (RELU_IN) {
                    hv.x = fmaxf(hv.x, 0.f); hv.y = fmaxf(hv.y, 0.f);
                    hv.z = fmaxf(hv.z, 0.f); hv.w = fmaxf(hv.w, 0.f);
                }
#pragma unroll
                for (int kk = 0; kk < 4; ++kk) {
                    aD0[m] = fmaf(hv[kk], wv[kk].x, aD0[m]);
                    aD1[m] = fmaf(hv[kk], wv[kk].y, aD1[m]);
                    aS0[m] = fmaf(hv[kk], wv[kk].z, aS0[m]);
                    aS1[m] = fmaf(hv[kk], wv[kk].w, aS1[m]);
                }
            }
        }
#pragma unroll
        for (int m = 0; m < 8; ++m) {
            const size_t n = base + m;
            *(f2*)&D[n * 128 + 2 * lane] = (f2){aD0[m], aD1[m]};
            *(f2*)&S[n * 128 + 2 * lane] = (f2){aS0[m], aS1[m]};
            if (RELU_IN) hout[n * HID + lane] = fmaxf(hin[n * HID + lane], 0.f);
        }
    }
}

// ---------------------------------------------------------------------------
// K3 (per layer): NODE-CENTRIC gather — no atomics.  One wave per dst node:
//   agg[n][c] = hres[n][c] + sum_{j in CSR[n]} sigmoid(f_j)*softplus(s_j)
//   f_j = bf[c] + D[n][2c]   + S[src_j][2c]   + ea[e_j] . Wf[128:169,c]
//   s_j = bs[c] + D[n][2c+1] + S[src_j][2c+1] + ea[e_j] . Ws[128:169,c]
// 82 weight columns pinned in VGPRs (launch_bounds caps at 128 VGPR,
// 4 waves/SIMD).  Edge rows are SGPR-uniform; 2-edge unroll for ILP.
// ---------------------------------------------------------------------------
__device__ __forceinline__ float act(float f, float s) {
    const float gate = __builtin_amdgcn_rcpf(1.f + __expf(-f));
    const float sp   = fmaxf(s, 0.f) + __logf(1.f + __expf(-fabsf(s)));
    return gate * sp;
}

__global__ __launch_bounds__(256, 4) void k_gather(const int2* __restrict__ csr,
                                                   const int* __restrict__ offs,
                                                   const float* __restrict__ ea,
                                                   const float* __restrict__ D,
                                                   const float* __restrict__ S,
                                                   const float* __restrict__ Wf,
                                                   const float* __restrict__ Ws,
                                                   const float* __restrict__ bf,
                                                   const float* __restrict__ bs,
                                                   const float* hres,
                                                   float* agg) {
    const int lane = threadIdx.x & 63;
    float wf[EDGE_F], ws[EDGE_F];
#pragma unroll
    for (int k = 0; k < EDGE_F; ++k) {
        wf[k] = Wf[(128 + k) * HID + lane];
        ws[k] = Ws[(128 + k) * HID + lane];
    }
    const float bfv = bf[lane], bsv = bs[lane];
    const int nW = gridDim.x * 4;
    for (int n0 = blockIdx.x * 4 + (threadIdx.x >> 6); n0 < N_NODES; n0 += nW) {
        const int n  = __builtin_amdgcn_readfirstlane(n0);
        const int j0 = offs[n];
        const int j1 = offs[n + 1];
        float acc = hres[(size_t)n * HID + lane];   // residual
        const f2 dv = *(const f2*)&D[(size_t)n * 128 + 2 * lane];
        const float bD0 = bfv + dv.x, bD1 = bsv + dv.y;
        int j = j0;
        for (; j + 1 < j1; j += 2) {
            const int2 c0 = csr[j], c1 = csr[j + 1];
            const int s0 = __builtin_amdgcn_readfirstlane(c0.x);
            const int e0 = __builtin_amdgcn_readfirstlane(c0.y);
            const int s1 = __builtin_amdgcn_readfirstlane(c1.x);
            const int e1 = __builtin_amdgcn_readfirstlane(c1.y);
            const f2 sv0 = *(const f2*)&S[(size_t)s0 * 128 + 2 * lane];
            const f2 sv1 = *(const f2*)&S[(size_t)s1 * 128 + 2 * lane];
            const float* r0 = ea + (size_t)e0 * EDGE_F;
            const float* r1 = ea + (size_t)e1 * EDGE_F;
            float f0 = bD0 + sv0.x, q0 = bD1 + sv0.y;
            float f1 = bD0 + sv1.x, q1 = bD1 + sv1.y;
#pragma unroll
            for (int k = 0; k < EDGE_F; ++k) {
                const float a = r0[k], b = r1[k];
                f0 = fmaf(a, wf[k], f0); q0 = fmaf(a, ws[k], q0);
                f1 = fmaf(b, wf[k], f1); q1 = fmaf(b, ws[k], q1);
            }
            acc += act(f0, q0) + act(f1, q1);
        }
        if (j < j1) {
            const int2 c0 = csr[j];
            const int s0 = __builtin_amdgcn_readfirstlane(c0.x);
            const int e0 = __builtin_amdgcn_readfirstlane(c0.y);
            const f2 sv0 = *(const f2*)&S[(size_t)s0 * 128 + 2 * lane];
            const float* r0 = ea + (size_t)e0 * EDGE_F;
            float f0 = bD0 + sv0.x, q0 = bD1 + sv0.y;
#pragma unroll
            for (int k = 0; k < EDGE_F; ++k) {
                const float a = r0[k];
                f0 = fmaf(a, wf[k], f0); q0 = fmaf(a, ws[k], q0);
            }
            acc += act(f0, q0);
        }
        agg[(size_t)n * HID + lane] = acc;
    }
}

// ---------------------------------------------------------------------------
// K5: pooled sums + counts; relu on the fly. batch sorted -> run-length.
// ---------------------------------------------------------------------------
__global__ __launch_bounds__(256) void k_pool(const float* __restrict__ agg,
                                              const int* __restrict__ batch,
                                              float* __restrict__ psum,
                                              float* __restrict__ pcnt) {
    const int lane = threadIdx.x & 63;
    const int wave = blockIdx.x * 4 + (threadIdx.x >> 6);
    const int nW   = gridDim.x * 4;
    const int chunk = (N_NODES + nW - 1) / nW;
    const int n0 = wave * chunk;
    if (n0 >= N_NODES) return;
    const int n1 = min(n0 + chunk, N_NODES);
    float acc = 0.f;
    int cur = batch[n0];
    int run = 0;
    for (int n = n0; n < n1; ++n) {
        const int g = batch[n];
        if (g != cur) {
            unsafeAtomicAdd(&psum[(size_t)cur * HID + lane], acc);
            if (lane == 0) unsafeAtomicAdd(&pcnt[cur], (float)run);
            acc = 0.f; run = 0; cur = g;
        }
        acc += fmaxf(agg[(size_t)n * HID + lane], 0.f);
        ++run;
    }
    unsafeAtomicAdd(&psum[(size_t)cur * HID + lane], acc);
    if (lane == 0) unsafeAtomicAdd(&pcnt[cur], (float)run);
}

// ---------------------------------------------------------------------------
// K6: head.  One thread per graph (256 threads, 1 block).
// ---------------------------------------------------------------------------
__global__ __launch_bounds__(256) void k_head(const float* __restrict__ psum,
                                              const float* __restrict__ pcnt,
                                              const float* __restrict__ l1W,
                                              const float* __restrict__ l1b,
                                              const float* __restrict__ l2W,
                                              const float* __restrict__ l2b,
                                              float* __restrict__ out) {
    const int g = threadIdx.x;
    const float inv = 1.f / fmaxf(pcnt[g], 1.f);
    float hid[32];
#pragma unroll
    for (int j = 0; j < 32; ++j) hid[j] = l1b[j];
    for (int c = 0; c < HID; ++c) {
        const float pv = psum[(size_t)g * HID + c] * inv;
#pragma unroll
        for (int j = 0; j < 32; ++j) hid[j] = fmaf(pv, l1W[c * 32 + j], hid[j]);
    }
#pragma unroll
    for (int j = 0; j < 32; ++j) hid[j] = fmaxf(hid[j], 0.f);
#pragma unroll
    for (int k = 0; k < 2; ++k) {
        float a = l2b[k];
#pragma unroll
        for (int j = 0; j < 32; ++j) a = fmaf(hid[j], l2W[j * 2 + k], a);
        out[g * 2 + k] = a;
    }
}

// ---------------------------------------------------------------------------
extern "C" void kernel_launch(void* const* d_in, const int* in_sizes, int n_in,
                              void* d_out, int out_size, void* d_ws, size_t ws_size,
                              hipStream_t stream) {
    const float* x     = (const float*)d_in[0];
    const int*   ei    = (const int*)d_in[1];
    const float* ea    = (const float*)d_in[2];
    const int*   batch = (const int*)d_in[3];
    const float* embW  = (const float*)d_in[4];
    const float* embb  = (const float*)d_in[5];
    const float* c1Wf  = (const float*)d_in[6];
    const float* c1bf  = (const float*)d_in[7];
    const float* c1Ws  = (const float*)d_in[8];
    const float* c1bs  = (const float*)d_in[9];
    const float* c2Wf  = (const float*)d_in[10];
    const float* c2bf  = (const float*)d_in[11];
    const float* c2Ws  = (const float*)d_in[12];
    const float* c2bs  = (const float*)d_in[13];
    const float* l1W   = (const float*)d_in[14];
    const float* l1b   = (const float*)d_in[15];
    const float* l2W   = (const float*)d_in[16];
    const float* l2b   = (const float*)d_in[17];
    float* out = (float*)d_out;

    char* w = (char*)d_ws;
    float* A    = (float*)w; w += (size_t)N_NODES * HID * sizeof(float);   // 25.6 MB
    float* D    = (float*)w; w += (size_t)N_NODES * 128 * sizeof(float);   // 51.2 MB
    float* S    = (float*)w; w += (size_t)N_NODES * 128 * sizeof(float);   // 51.2 MB
    int2*  csr  = (int2*)w;  w += (size_t)N_EDGES * sizeof(int2);          // 12.8 MB
    int*   cnt  = (int*)w;   w += (size_t)((N_NODES + 4) & ~3) * sizeof(int);
    int*   offs = (int*)w;   w += (size_t)((N_NODES + 4) & ~3) * sizeof(int);
    int*   woffs= (int*)w;   w += (size_t)((N_NODES + 4) & ~3) * sizeof(int);
    int*   csum = (int*)w;   w += 128 * sizeof(int);
    int*   cbase= (int*)w;   w += 128 * sizeof(int);
    float* psum = (float*)w; w += (size_t)N_GRAPHS * HID * sizeof(float);
    float* pcnt = (float*)w; w += (size_t)N_GRAPHS * sizeof(float);

    hipMemsetAsync(cnt, 0, (size_t)N_NODES * sizeof(int), stream);
    hipMemsetAsync(psum, 0, (size_t)(N_GRAPHS * HID + N_GRAPHS) * sizeof(float), stream);

    // ---- embed + CSR build (CSR shared by both layers) ----
    k_embed<<<1024, 256, 0, stream>>>(x, embW, embb, A);
    k_hist<<<1024, 256, 0, stream>>>(ei, cnt);
    k_scan1<<<NCHUNK, 256, 0, stream>>>(cnt, csum);
    k_scan2<<<1, 128, 0, stream>>>(csum, cbase);
    k_scan3<<<NCHUNK, 256, 0, stream>>>(cnt, cbase, offs, woffs);
    k_scatter<<<1024, 256, 0, stream>>>(ei, woffs, csr);

    // ---- CGConv layer 1 (gather writes A in place: own-row read precedes write) ----
    k_node_pre<0><<<1024, 256, 0, stream>>>(A, A, c1Wf, c1Ws, D, S);
    k_gather<<<2048, 256, 0, stream>>>(csr, offs, ea, D, S, c1Wf, c1Ws, c1bf, c1bs, A, A);

    // ---- CGConv layer 2 (relu fused into precompute, in place) ----
    k_node_pre<1><<<1024, 256, 0, stream>>>(A, A, c2Wf, c2Ws, D, S);
    k_gather<<<2048, 256, 0, stream>>>(csr, offs, ea, D, S, c2Wf, c2Ws, c2bf, c2bs, A, A);

    // ---- pool (relu fused) + head ----
    k_pool<<<512, 256, 0, stream>>>(A, batch, psum, pcnt);
    k_head<<<1, 256, 0, stream>>>(psum, pcnt, l1W, l1b, l2W, l2b, out);
}